// Round 7
// baseline (668.395 us; speedup 1.0000x reference)
//
#include <hip/hip_runtime.h>

#define T_TOK 4096
#define E_EXP 32
#define HDIM  2048
#define IDIM  1024
#define TKROW 16384   // T_TOK * 4
#define BM    128
#define MAXT  160     // 16384/128 + 32 worst case

typedef __attribute__((ext_vector_type(8))) short   short8;
typedef __attribute__((ext_vector_type(8))) __bf16  bf16x8;
typedef __attribute__((ext_vector_type(4))) float   f32x4;

typedef const __attribute__((address_space(1))) unsigned int* gas_t;
typedef __attribute__((address_space(3))) unsigned int*       las_t;

static __device__ __forceinline__ void gload16(const void* g, void* l) {
    __builtin_amdgcn_global_load_lds((gas_t)(uintptr_t)g, (las_t)(uintptr_t)l, 16, 0, 0);
}

static __device__ __forceinline__ f32x4 mfma16(short8 a, short8 b, f32x4 c) {
    return __builtin_amdgcn_mfma_f32_16x16x32_bf16(
        __builtin_bit_cast(bf16x8, a), __builtin_bit_cast(bf16x8, b), c, 0, 0, 0);
}

static __device__ __forceinline__ unsigned short f2bf(float f) {
    unsigned u = __builtin_bit_cast(unsigned, f);
    unsigned r = (u + 0x7FFFu + ((u >> 16) & 1u)) >> 16;
    return (unsigned short)r;
}
static __device__ __forceinline__ float bf2f(unsigned short u) {
    return __builtin_bit_cast(float, ((unsigned)u) << 16);
}
static __device__ __forceinline__ unsigned cvtpk(float lo, float hi) {
    unsigned r;
    asm("v_cvt_pk_bf16_f32 %0, %1, %2" : "=v"(r) : "v"(lo), "v"(hi));
    return r;
}
// pack 8 f32 -> short8 (bf16), RNE
static __device__ __forceinline__ short8 pack8(float v0, float v1, float v2, float v3,
                                               float v4, float v5, float v6, float v7) {
    uint4 u;
    u.x = cvtpk(v0, v1); u.y = cvtpk(v2, v3);
    u.z = cvtpk(v4, v5); u.w = cvtpk(v6, v7);
    return __builtin_bit_cast(short8, u);
}

#define VM0()   asm volatile("s_waitcnt vmcnt(0)" ::: "memory")
#define BAR()   do { __builtin_amdgcn_s_barrier(); __builtin_amdgcn_sched_barrier(0); } while (0)

// ---------------- gating: logits -> top4 -> softmax ----------------
__global__ __launch_bounds__(256) void gating_kernel(
    const float* __restrict__ x, const float* __restrict__ gw,
    const float* __restrict__ gb, int* __restrict__ topk_idx,
    float* __restrict__ topk_w)
{
    int wave = threadIdx.x >> 6, lane = threadIdx.x & 63;
    int t = blockIdx.x * 4 + wave;
    const float* xr = x + (size_t)t * HDIM;
    float xv[32];
#pragma unroll
    for (int j = 0; j < 32; j++) xv[j] = xr[lane + 64 * j];
    float logits[E_EXP];
#pragma unroll
    for (int e = 0; e < E_EXP; e++) {
        const float* wr = gw + (size_t)e * HDIM;
        float s = 0.f;
#pragma unroll
        for (int j = 0; j < 32; j++) s = fmaf(xv[j], wr[lane + 64 * j], s);
#pragma unroll
        for (int off = 32; off; off >>= 1) s += __shfl_xor(s, off);
        logits[e] = s + gb[e];
    }
    unsigned sel = 0;
    float v[4]; int id[4];
#pragma unroll
    for (int kk = 0; kk < 4; kk++) {
        float best = -3.4e38f; int bi = 0;
#pragma unroll
        for (int e = 0; e < E_EXP; e++) {
            bool ok = ((sel >> e) & 1u) == 0u;
            bool gt = ok && (logits[e] > best);
            best = gt ? logits[e] : best;
            bi   = gt ? e : bi;
        }
        sel |= 1u << bi; v[kk] = best; id[kk] = bi;
    }
    float m0 = v[0];
    float e0 = __expf(v[0] - m0), e1 = __expf(v[1] - m0);
    float e2 = __expf(v[2] - m0), e3 = __expf(v[3] - m0);
    float inv = 1.f / (e0 + e1 + e2 + e3);
    if (lane == 0) {
        int b4 = t * 4;
        topk_idx[b4 + 0] = id[0]; topk_w[b4 + 0] = e0 * inv;
        topk_idx[b4 + 1] = id[1]; topk_w[b4 + 1] = e1 * inv;
        topk_idx[b4 + 2] = id[2]; topk_w[b4 + 2] = e2 * inv;
        topk_idx[b4 + 3] = id[3]; topk_w[b4 + 3] = e3 * inv;
    }
}

// ---------------- small bookkeeping kernels ----------------
__global__ void init_kernel(int* counts, int* fill) {
    if (threadIdx.x < E_EXP) { counts[threadIdx.x] = 0; fill[threadIdx.x] = 0; }
}

__global__ void histo_kernel(const int* __restrict__ idx, int* counts) {
    int i = blockIdx.x * 256 + threadIdx.x;
    atomicAdd(&counts[idx[i]], 1);
}

__global__ void scan_tiles_kernel(const int* counts, int* offsets,
                                  int* tile_e, int* tile_r, int* ntiles) {
    if (threadIdx.x == 0) {
        int acc = 0;
        for (int e = 0; e < E_EXP; e++) { offsets[e] = acc; acc += counts[e]; }
        offsets[E_EXP] = acc;
        int nt = 0;
        for (int e = 0; e < E_EXP; e++) {
            int c = counts[e];
            for (int r = 0; r < c; r += BM) {
                tile_e[nt] = e; tile_r[nt] = offsets[e] + r; nt++;
            }
        }
        ntiles[0] = nt;
    }
}

__global__ void scatter_kernel(const int* __restrict__ idx, const int* __restrict__ offsets,
                               int* fill, int* __restrict__ pos_of, int* __restrict__ row_tok) {
    int i = blockIdx.x * 256 + threadIdx.x;
    int e = idx[i];
    int pos = offsets[e] + atomicAdd(&fill[e], 1);
    pos_of[i] = pos;
    row_tok[pos] = i >> 2;
}

__global__ __launch_bounds__(64) void gather_kernel(
    const float* __restrict__ x, const int* __restrict__ row_tok,
    unsigned short* __restrict__ xt)
{
    int r = blockIdx.x, lane = threadIdx.x;
    const f32x4* src = (const f32x4*)(x + (size_t)row_tok[r] * HDIM);
    unsigned short* dst = xt + (size_t)r * HDIM;
#pragma unroll
    for (int j = 0; j < 8; j++) {
        f32x4 f = src[lane + 64 * j];
        uint2 o;
        o.x = cvtpk(f[0], f[1]);
        o.y = cvtpk(f[2], f[3]);
        *(uint2*)(dst + 4 * (lane + 64 * j)) = o;
    }
}

// =====================================================================
// grouped GEMM 1 (fused SwiGLU): BM=128, BN=128 (gate & up), BK=32.
// 512 thr / 8 waves (2m x 4n), wave tile 64x32 per matrix.
// LDS 80KB total -> 2 blocks/CU. All staging via global_load_lds;
// B kept f32 in LDS ([k][n], no transpose), converted at frag read.
// 1-deep pipeline: issue(t+1) -> MFMA(t) -> vmcnt(0) -> barrier.
// Cross-block overlap (2 blocks/CU) hides the drain.
// =====================================================================
__global__ __launch_bounds__(512, 4) void gemm1_kernel(
    const unsigned short* __restrict__ xt, const float* __restrict__ w_gate,
    const float* __restrict__ b_gate, const float* __restrict__ w_up,
    const float* __restrict__ b_up, const int* __restrict__ tile_e,
    const int* __restrict__ tile_r, const int* __restrict__ ntiles,
    const int* __restrict__ offsets, const int* __restrict__ counts,
    unsigned short* __restrict__ act)
{
    int flat = blockIdx.y * 8 + blockIdx.x;            // 0..1279
    int swz = (flat & 7) * MAXT + (flat >> 3);         // bijective (1280 = 8*160)
    int tid = swz >> 3, nb = swz & 7;
    if (tid >= ntiles[0]) return;
    int e = tile_e[tid], row0 = tile_r[tid];
    int cnt_end = offsets[e] + counts[e];
    int n0 = nb * 128;

    __shared__ unsigned short As[2][BM * 32];   // 16 KB
    __shared__ float Bg[2][32 * 128];           // 32 KB
    __shared__ float Bu[2][32 * 128];           // 32 KB  -> 80 KB total

    int t = threadIdx.x, lane = t & 63, w = t >> 6;
    int wr = w >> 2, wc = w & 3;
    int lrow = lane & 15;
    int kf8 = (lane >> 4) * 8;

    f32x4 accg[4][2], accu[4][2];
#pragma unroll
    for (int m = 0; m < 4; m++)
#pragma unroll
        for (int n = 0; n < 2; n++) { accg[m][n] = (f32x4)0.f; accu[m][n] = (f32x4)0.f; }

    // A staging: wave w covers rows 16w..16w+15; lane -> row 16w+(lane>>2), chunk lane&3
    int arow = row0 + 16 * w + (lane >> 2);
    if (arow > TKROW - 1) arow = TKROW - 1;
    const unsigned short* aSrc = xt + (size_t)arow * HDIM + (lane & 3) * 8;
    // B staging: per matrix, wave w covers k-rows 4w..4w+3, 2 gloads (2 rows each)
    //   lane -> row-sub (lane>>5), chunk (lane&31)
    size_t eBase = (size_t)e * ((size_t)HDIM * IDIM);
    const float* gSrc = w_gate + eBase + (size_t)(4 * w + (lane >> 5)) * IDIM + n0 + (lane & 31) * 4;
    const float* uSrc = w_up   + eBase + (size_t)(4 * w + (lane >> 5)) * IDIM + n0 + (lane & 31) * 4;

#define G1_STAGE(KT, BUF) do { \
    gload16(aSrc + (size_t)(KT) * 32, (void*)&As[BUF][(16 * w) * 32]); \
    _Pragma("unroll") for (int i_ = 0; i_ < 2; i_++) { \
        size_t ko_ = (size_t)(KT) * 32 * IDIM + (size_t)(2 * i_) * IDIM; \
        gload16(gSrc + ko_, (void*)&Bg[BUF][(4 * w + 2 * i_) * 128]); \
        gload16(uSrc + ko_, (void*)&Bu[BUF][(4 * w + 2 * i_) * 128]); \
    } } while (0)

#define G1_MFMA(BUF) do { \
    const unsigned short* Ab_ = &As[BUF][0]; \
    const float* Bgb_ = &Bg[BUF][0]; const float* Bub_ = &Bu[BUF][0]; \
    short8 bgf_[2], buf_[2]; \
    _Pragma("unroll") for (int nf_ = 0; nf_ < 2; nf_++) { \
        int nc_ = wc * 32 + nf_ * 16 + lrow; \
        bgf_[nf_] = pack8(Bgb_[(kf8 + 0) * 128 + nc_], Bgb_[(kf8 + 1) * 128 + nc_], \
                          Bgb_[(kf8 + 2) * 128 + nc_], Bgb_[(kf8 + 3) * 128 + nc_], \
                          Bgb_[(kf8 + 4) * 128 + nc_], Bgb_[(kf8 + 5) * 128 + nc_], \
                          Bgb_[(kf8 + 6) * 128 + nc_], Bgb_[(kf8 + 7) * 128 + nc_]); \
        buf_[nf_] = pack8(Bub_[(kf8 + 0) * 128 + nc_], Bub_[(kf8 + 1) * 128 + nc_], \
                          Bub_[(kf8 + 2) * 128 + nc_], Bub_[(kf8 + 3) * 128 + nc_], \
                          Bub_[(kf8 + 4) * 128 + nc_], Bub_[(kf8 + 5) * 128 + nc_], \
                          Bub_[(kf8 + 6) * 128 + nc_], Bub_[(kf8 + 7) * 128 + nc_]); \
    } \
    __builtin_amdgcn_s_setprio(1); \
    _Pragma("unroll") for (int m_ = 0; m_ < 4; m_++) { \
        int rr_ = wr * 64 + m_ * 16 + lrow; \
        short8 af_ = *(const short8*)&Ab_[rr_ * 32 + kf8]; \
        _Pragma("unroll") for (int nf_ = 0; nf_ < 2; nf_++) { \
            accg[m_][nf_] = mfma16(af_, bgf_[nf_], accg[m_][nf_]); \
            accu[m_][nf_] = mfma16(af_, buf_[nf_], accu[m_][nf_]); \
        } \
    } \
    __builtin_amdgcn_s_setprio(0); } while (0)

    G1_STAGE(0, 0);
    VM0(); BAR();
    int cur = 0;
#pragma unroll 1
    for (int kt = 0; kt < 64; kt++) {
        if (kt + 1 < 64) G1_STAGE(kt + 1, cur ^ 1);
        G1_MFMA(cur);
        VM0(); BAR();
        cur ^= 1;
    }
#undef G1_STAGE
#undef G1_MFMA

    // epilogue: fused SwiGLU
#pragma unroll
    for (int nf = 0; nf < 2; nf++) {
        int col = n0 + wc * 32 + nf * 16 + lrow;
        float bgv = b_gate[e * IDIM + col];
        float buv = b_up[e * IDIM + col];
#pragma unroll
        for (int m = 0; m < 4; m++) {
            int rb = row0 + wr * 64 + m * 16 + (lane >> 4) * 4;
#pragma unroll
            for (int r = 0; r < 4; r++) {
                int grow = rb + r;
                if (grow < cnt_end) {
                    float gv = accg[m][nf][r] + bgv;
                    float uv = accu[m][nf][r] + buv;
                    gv = fminf(gv, 7.f);
                    uv = fminf(fmaxf(uv, -7.f), 7.f);
                    float glu = gv / (1.f + __expf(-1.702f * gv));
                    act[(size_t)grow * IDIM + col] = f2bf((uv + 1.f) * glu);
                }
            }
        }
    }
}

// =====================================================================
// grouped GEMM 2: outs = act @ w_down + b_down
// BM=128, BN=256, BK=32, 512 thr / 8 waves (2m x 4n), wave tile 64x64.
// Same structure: 80KB LDS, 2 blocks/CU, f32 B in LDS.
// =====================================================================
__global__ __launch_bounds__(512, 4) void gemm2_kernel(
    const unsigned short* __restrict__ actb, const float* __restrict__ w_down,
    const float* __restrict__ b_down, const int* __restrict__ tile_e,
    const int* __restrict__ tile_r, const int* __restrict__ ntiles,
    const int* __restrict__ offsets, const int* __restrict__ counts,
    unsigned short* __restrict__ outs)
{
    int flat = blockIdx.y * 8 + blockIdx.x;
    int swz = (flat & 7) * MAXT + (flat >> 3);
    int tid = swz >> 3, nb = swz & 7;
    if (tid >= ntiles[0]) return;
    int e = tile_e[tid], row0 = tile_r[tid];
    int cnt_end = offsets[e] + counts[e];
    int n0 = nb * 256;

    __shared__ unsigned short As[2][BM * 32];   // 16 KB
    __shared__ float Bs[2][32 * 256];           // 64 KB -> 80 KB total

    int t = threadIdx.x, lane = t & 63, w = t >> 6;
    int wr = w >> 2, wc = w & 3;
    int lrow = lane & 15;
    int kf8 = (lane >> 4) * 8;

    f32x4 acc[4][4];
#pragma unroll
    for (int m = 0; m < 4; m++)
#pragma unroll
        for (int n = 0; n < 4; n++) acc[m][n] = (f32x4)0.f;

    int arow = row0 + 16 * w + (lane >> 2);
    if (arow > TKROW - 1) arow = TKROW - 1;
    const unsigned short* aSrc = actb + (size_t)arow * IDIM + (lane & 3) * 8;
    // B staging: wave w covers k-rows 4w..4w+3, 1 gload per row (1KB row)
    const float* dSrc = w_down + (size_t)e * ((size_t)IDIM * HDIM)
                        + (size_t)(4 * w) * HDIM + n0 + lane * 4;

#define G2_STAGE(KT, BUF) do { \
    gload16(aSrc + (size_t)(KT) * 32, (void*)&As[BUF][(16 * w) * 32]); \
    _Pragma("unroll") for (int i_ = 0; i_ < 4; i_++) { \
        gload16(dSrc + (size_t)(KT) * 32 * HDIM + (size_t)i_ * HDIM, \
                (void*)&Bs[BUF][(4 * w + i_) * 256]); \
    } } while (0)

#define G2_MFMA(BUF) do { \
    const unsigned short* Ab_ = &As[BUF][0]; \
    const float* Bb_ = &Bs[BUF][0]; \
    short8 bf_[4]; \
    _Pragma("unroll") for (int nf_ = 0; nf_ < 4; nf_++) { \
        int nc_ = wc * 64 + nf_ * 16 + lrow; \
        bf_[nf_] = pack8(Bb_[(kf8 + 0) * 256 + nc_], Bb_[(kf8 + 1) * 256 + nc_], \
                         Bb_[(kf8 + 2) * 256 + nc_], Bb_[(kf8 + 3) * 256 + nc_], \
                         Bb_[(kf8 + 4) * 256 + nc_], Bb_[(kf8 + 5) * 256 + nc_], \
                         Bb_[(kf8 + 6) * 256 + nc_], Bb_[(kf8 + 7) * 256 + nc_]); \
    } \
    __builtin_amdgcn_s_setprio(1); \
    _Pragma("unroll") for (int m_ = 0; m_ < 4; m_++) { \
        int rr_ = wr * 64 + m_ * 16 + lrow; \
        short8 af_ = *(const short8*)&Ab_[rr_ * 32 + kf8]; \
        _Pragma("unroll") for (int nf_ = 0; nf_ < 4; nf_++) \
            acc[m_][nf_] = mfma16(af_, bf_[nf_], acc[m_][nf_]); \
    } \
    __builtin_amdgcn_s_setprio(0); } while (0)

    G2_STAGE(0, 0);
    VM0(); BAR();
    int cur = 0;
#pragma unroll 1
    for (int kt = 0; kt < 32; kt++) {
        if (kt + 1 < 32) G2_STAGE(kt + 1, cur ^ 1);
        G2_MFMA(cur);
        VM0(); BAR();
        cur ^= 1;
    }
#undef G2_STAGE
#undef G2_MFMA

#pragma unroll
    for (int nf = 0; nf < 4; nf++) {
        int col = n0 + wc * 64 + nf * 16 + lrow;
        float bdv = b_down[e * HDIM + col];
#pragma unroll
        for (int m = 0; m < 4; m++) {
            int rb = row0 + wr * 64 + m * 16 + (lane >> 4) * 4;
#pragma unroll
            for (int r = 0; r < 4; r++) {
                int grow = rb + r;
                if (grow < cnt_end)
                    outs[(size_t)grow * HDIM + col] = f2bf(acc[m][nf][r] + bdv);
            }
        }
    }
}

// ---------------- combine ----------------
__global__ __launch_bounds__(256) void combine_kernel(
    const unsigned short* __restrict__ outs, const int* __restrict__ pos_of,
    const float* __restrict__ topk_w, float* __restrict__ y)
{
    int tok = blockIdx.x;
    int c0 = threadIdx.x * 8;
    float acc[8] = {0.f, 0.f, 0.f, 0.f, 0.f, 0.f, 0.f, 0.f};
#pragma unroll
    for (int k = 0; k < 4; k++) {
        int pos = pos_of[tok * 4 + k];
        float w = topk_w[tok * 4 + k];
        short8 vv = *(const short8*)(outs + (size_t)pos * HDIM + c0);
#pragma unroll
        for (int j = 0; j < 8; j++)
            acc[j] = fmaf(w, bf2f((unsigned short)vv[j]), acc[j]);
    }
    float4 o0 = make_float4(acc[0], acc[1], acc[2], acc[3]);
    float4 o1 = make_float4(acc[4], acc[5], acc[6], acc[7]);
    *(float4*)(y + (size_t)tok * HDIM + c0)     = o0;
    *(float4*)(y + (size_t)tok * HDIM + c0 + 4) = o1;
}

// ---------------- launch ----------------
extern "C" void kernel_launch(void* const* d_in, const int* in_sizes, int n_in,
                              void* d_out, int out_size, void* d_ws, size_t ws_size,
                              hipStream_t stream) {
    const float* x      = (const float*)d_in[0];
    const float* gw     = (const float*)d_in[1];
    const float* gb     = (const float*)d_in[2];
    const float* w_gate = (const float*)d_in[3];
    const float* b_gate = (const float*)d_in[4];
    const float* w_up   = (const float*)d_in[5];
    const float* b_up   = (const float*)d_in[6];
    const float* w_down = (const float*)d_in[7];
    const float* b_down = (const float*)d_in[8];
    float* y = (float*)d_out;

    char* base = (char*)d_ws;
    size_t off = 0;
    int*   topk_idx = (int*)(base + off);   off += (size_t)TKROW * 4;
    float* topk_w   = (float*)(base + off); off += (size_t)TKROW * 4;
    int*   counts   = (int*)(base + off);   off += 256;
    int*   offsets  = (int*)(base + off);   off += 256;
    int*   fill     = (int*)(base + off);   off += 256;
    int*   ntiles   = (int*)(base + off);   off += 256;
    int*   tile_e   = (int*)(base + off);   off += 1024;
    int*   tile_r   = (int*)(base + off);   off += 1024;
    int*   pos_of   = (int*)(base + off);   off += (size_t)TKROW * 4;
    int*   row_tok  = (int*)(base + off);   off += (size_t)TKROW * 4;
    unsigned short* xt   = (unsigned short*)(base + off); off += (size_t)TKROW * HDIM * 2;
    unsigned short* act  = (unsigned short*)(base + off); off += (size_t)TKROW * IDIM * 2;
    unsigned short* outs = (unsigned short*)(base + off); off += (size_t)TKROW * HDIM * 2;

    init_kernel<<<1, 64, 0, stream>>>(counts, fill);
    gating_kernel<<<T_TOK / 4, 256, 0, stream>>>(x, gw, gb, topk_idx, topk_w);
    histo_kernel<<<TKROW / 256, 256, 0, stream>>>(topk_idx, counts);
    scan_tiles_kernel<<<1, 64, 0, stream>>>(counts, offsets, tile_e, tile_r, ntiles);
    scatter_kernel<<<TKROW / 256, 256, 0, stream>>>(topk_idx, offsets, fill, pos_of, row_tok);
    gather_kernel<<<TKROW, 64, 0, stream>>>(x, row_tok, xt);
    gemm1_kernel<<<dim3(8, MAXT), 512, 0, stream>>>(
        xt, w_gate, b_gate, w_up, b_up, tile_e, tile_r, ntiles, offsets, counts, act);
    gemm2_kernel<<<dim3(8, MAXT), 512, 0, stream>>>(
        act, w_down, b_down, tile_e, tile_r, ntiles, offsets, counts, outs);
    combine_kernel<<<T_TOK, 256, 0, stream>>>(outs, pos_of, topk_w, y);
}